// Round 9
// baseline (388.773 us; speedup 1.0000x reference)
//
#include <hip/hip_runtime.h>
#include <hip/hip_bf16.h>
#include <stdint.h>

// Problem constants
#define B_  64
#define T_  1000
#define DC_ 512
#define DM_ 80
#define DP_ 128
#define DH_ 128
#define DA_ 128
#define DRN 1024
#define G4  4096
#define SPLIT 262144              // one gate split buffer: 64 x 4096 f32

typedef __hip_bfloat16 bf16;
typedef unsigned short u16;
typedef unsigned int   u32;

// MFMA fragment types
typedef short bf8_t __attribute__((ext_vector_type(8)));
typedef float f4_t  __attribute__((ext_vector_type(4)));

// out element offsets: x_dec, ctx, w_new, h0n, c0n, h1n, c1n
#define O_XDEC 0
#define O_CTX  163840
#define O_WN   196608
#define O_H0   260608
#define O_C0   326144
#define O_H1   391680
#define O_C1   457216

__device__ __forceinline__ float b2f(bf16 v) { return __bfloat162float(v); }
__device__ __forceinline__ bf16  f2b(float v) { return __float2bfloat16(v); }
__device__ __forceinline__ u16   f2bu(float v) { return __builtin_bit_cast(u16, __float2bfloat16(v)); }

__device__ __forceinline__ float ldv(const float* p, size_t i) { return p[i]; }
__device__ __forceinline__ float ldv(const bf16*  p, size_t i) { return b2f(p[i]); }
__device__ __forceinline__ void  stv(float* p, size_t i, float v) { p[i] = v; }
__device__ __forceinline__ void  stv(bf16*  p, size_t i, float v) { p[i] = f2b(v); }

// load 8 consecutive elems as f32
template<typename T>
__device__ __forceinline__ void ld8f(const T* p, size_t i, float* o) {
    if constexpr (sizeof(T) == 2) {
        uint4 u = *(const uint4*)((const u16*)p + i);
        o[0] = __uint_as_float(u.x << 16); o[1] = __uint_as_float(u.x & 0xffff0000u);
        o[2] = __uint_as_float(u.y << 16); o[3] = __uint_as_float(u.y & 0xffff0000u);
        o[4] = __uint_as_float(u.z << 16); o[5] = __uint_as_float(u.z & 0xffff0000u);
        o[6] = __uint_as_float(u.w << 16); o[7] = __uint_as_float(u.w & 0xffff0000u);
    } else {
        float4 a = *(const float4*)(p + i);
        float4 b = *(const float4*)(p + i + 4);
        o[0]=a.x; o[1]=a.y; o[2]=a.z; o[3]=a.w; o[4]=b.x; o[5]=b.y; o[6]=b.z; o[7]=b.w;
    }
}
__device__ __forceinline__ void ld8f_bits(const u16* p, size_t i, float* o) {
    uint4 u = *(const uint4*)(p + i);
    o[0] = __uint_as_float(u.x << 16); o[1] = __uint_as_float(u.x & 0xffff0000u);
    o[2] = __uint_as_float(u.y << 16); o[3] = __uint_as_float(u.y & 0xffff0000u);
    o[4] = __uint_as_float(u.z << 16); o[5] = __uint_as_float(u.z & 0xffff0000u);
    o[6] = __uint_as_float(u.w << 16); o[7] = __uint_as_float(u.w & 0xffff0000u);
}

// ---------------- per-block dtype sniff (proven heuristic; wave-uniform) -----
__device__ __forceinline__ bool sniff_is_f32(const u32* h0raw) {
    int lane = threadIdx.x & 63;
    int c = 0;
    #pragma unroll
    for (int i = 0; i < 4; ++i) {
        u32 e = (h0raw[lane * 4 + i] >> 7) & 0xFF;
        c += (e >= 100 && e <= 126) ? 1 : 0;
    }
    #pragma unroll
    for (int s = 1; s < 64; s <<= 1) c += __shfl_xor(c, s);
    return c < 128;
}

// ---------------- Threefry-2x32 (bit-exact vs JAX — do not touch) ------------
__device__ __forceinline__ u32 rotl32(u32 v, int r) { return (v << r) | (v >> (32 - r)); }
__device__ __forceinline__ void threefry2x32(u32 k0, u32 k1, u32 x0, u32 x1, u32& y0, u32& y1) {
    u32 ks2 = k0 ^ k1 ^ 0x1BD11BDAu;
    x0 += k0; x1 += k1;
#define TF_R(r) { x0 += x1; x1 = rotl32(x1, r); x1 ^= x0; }
    TF_R(13) TF_R(15) TF_R(26) TF_R(6)
    x0 += k1; x1 += ks2 + 1u;
    TF_R(17) TF_R(29) TF_R(16) TF_R(24)
    x0 += ks2; x1 += k0 + 2u;
    TF_R(13) TF_R(15) TF_R(26) TF_R(6)
    x0 += k0; x1 += k1 + 3u;
    TF_R(17) TF_R(29) TF_R(16) TF_R(24)
    x0 += k1; x1 += ks2 + 4u;
    TF_R(13) TF_R(15) TF_R(26) TF_R(6)
    x0 += ks2; x1 += k0 + 5u;
#undef TF_R
    y0 = x0; y1 = x1;
}
__device__ __forceinline__ float dropout_mask(int which, int j) {
    u32 dk0, dk1, b1, b2;
    threefry2x32(0u, 42u, 0u, (u32)which, dk0, dk1);
    threefry2x32(dk0, dk1, 0u, (u32)j, b1, b2);
    u32 bits = b1 ^ b2;
    float u = __uint_as_float((bits >> 9) | 0x3f800000u) - 1.0f;
    return (u < 0.5f) ? 2.0f : 0.0f;
}

// ============== L0: prep = btprep(0..31) + prenet(32..95) + h-GEMMs(96..607) =
// h-GEMM: C_split = hprev[64][1024] @ Whh[1024][4096] — depends only on
// launch-time inputs, so it runs here, overlapped, off the critical path.
// unit u: n-tile = u&63, split = u>>6 (4 splits x 4 chunks of 64 k-rows).
template<typename T>
__device__ void hgemm_impl(const T* hprev, const T* Whh, float* GsL, int unit,
                           float (*As)[66], float (*Ws)[64]) {
    int tid = threadIdx.x;
    int n0b = (unit & 63) * 64;
    int split = unit >> 6;              // 0..3
    int kbase = split * 256;
    int cx = tid & 15, ry = tid >> 4;
    int b0 = ry * 4, n0 = cx * 4;
    int a_bb = tid >> 2, a_k16 = (tid & 3) * 16;
    int w_k  = tid >> 2, w_n16 = (tid & 3) * 16;
    float acc[4][4] = {};
    float va[16], vw[16];
#define HGLOAD(CH) do {                                                         \
        int k0 = kbase + (CH) * 64;                                             \
        ld8f(hprev, (size_t)a_bb * DRN + k0 + a_k16, va);                       \
        ld8f(hprev, (size_t)a_bb * DRN + k0 + a_k16 + 8, va + 8);               \
        const T* wr = Whh + (size_t)(k0 + w_k) * G4;                            \
        ld8f(wr, n0b + w_n16, vw);                                              \
        ld8f(wr, n0b + w_n16 + 8, vw + 8);                                      \
    } while (0)
    HGLOAD(0);
    for (int ch = 0; ch < 4; ++ch) {
        __syncthreads();
        #pragma unroll
        for (int j = 0; j < 16; ++j) As[a_bb][a_k16 + j] = va[j];
        #pragma unroll
        for (int j = 0; j < 16; ++j) Ws[w_k][w_n16 + j] = vw[j];
        __syncthreads();
        if (ch + 1 < 4) HGLOAD(ch + 1);
        #pragma unroll
        for (int kk = 0; kk < 64; kk += 2) {
            float2 av[4];
            #pragma unroll
            for (int r = 0; r < 4; ++r) av[r] = *(const float2*)&As[b0 + r][kk];
            float4 w0 = *(const float4*)&Ws[kk][n0];
            float4 w1 = *(const float4*)&Ws[kk + 1][n0];
            #pragma unroll
            for (int r = 0; r < 4; ++r) {
                acc[r][0] = fmaf(av[r].x, w0.x, acc[r][0]); acc[r][0] = fmaf(av[r].y, w1.x, acc[r][0]);
                acc[r][1] = fmaf(av[r].x, w0.y, acc[r][1]); acc[r][1] = fmaf(av[r].y, w1.y, acc[r][1]);
                acc[r][2] = fmaf(av[r].x, w0.z, acc[r][2]); acc[r][2] = fmaf(av[r].y, w1.z, acc[r][2]);
                acc[r][3] = fmaf(av[r].x, w0.w, acc[r][3]); acc[r][3] = fmaf(av[r].y, w1.w, acc[r][3]);
            }
        }
    }
#undef HGLOAD
    float* outp = GsL + (size_t)split * (64 * G4);
    #pragma unroll
    for (int r = 0; r < 4; ++r)
        *(float4*)&outp[(size_t)(b0 + r) * G4 + n0b + n0] =
            make_float4(acc[r][0], acc[r][1], acc[r][2], acc[r][3]);
}

template<typename T>
__device__ void prep_impl(const T* wm, u16* BTwm,
                          const T* x, const T* w1, const T* pb1, const T* w2, const T* pb2,
                          u16* Ab0, const T* h0p, const T* whh0, const T* h1p, const T* whh1,
                          float* GS, float (*As)[66], float (*Ws)[64]) {
    int bid = blockIdx.x, tid = threadIdx.x;
    if (bid < 32) {
        int gid = bid * 256 + tid;          // < 8192
        int L = gid & 63, kc = (gid >> 6) & 15, at = gid >> 10;
        u16* dst = BTwm + (size_t)gid * 8;
        int col = at * 16 + (L & 15);
        int krow = kc * 32 + (L >> 4) * 8;
        u16 v[8];
        #pragma unroll
        for (int j = 0; j < 8; ++j) v[j] = f2bu(ldv(wm, (size_t)(krow + j) * DA_ + col));
        uint4 pk;
        pk.x = v[0] | ((u32)v[1] << 16); pk.y = v[2] | ((u32)v[3] << 16);
        pk.z = v[4] | ((u32)v[5] << 16); pk.w = v[6] | ((u32)v[7] << 16);
        *(uint4*)dst = pk;
    } else if (bid < 96) {
        int b = bid - 32;
        float* xs = &As[0][0];        // [80]
        float* hs = xs + DM_;         // [128]
        if (tid < DM_) xs[tid] = ldv(x, (size_t)b * DM_ + tid);
        __syncthreads();
        if (tid < DH_) {
            float acc = ldv(pb1, tid);
            #pragma unroll 8
            for (int k = 0; k < DM_; ++k) acc = fmaf(xs[k], ldv(w1, (size_t)k * DH_ + tid), acc);
            acc = fmaxf(acc, 0.f) * dropout_mask(0, b * DH_ + tid);
            hs[tid] = acc;
        }
        __syncthreads();
        if (tid < DP_) {
            float acc2 = ldv(pb2, tid);
            #pragma unroll 8
            for (int k = 0; k < DH_; ++k) acc2 = fmaf(hs[k], ldv(w2, (size_t)k * DP_ + tid), acc2);
            acc2 = fmaxf(acc2, 0.f) * dropout_mask(1, b * DP_ + tid);
            Ab0[(size_t)b * 1664 + tid] = f2bu(acc2);
        }
    } else if (bid < 352) {
        hgemm_impl<T>(h0p, whh0, GS, bid - 96, As, Ws);               // splits 0..3
    } else {
        hgemm_impl<T>(h1p, whh1, GS + (size_t)6 * SPLIT, bid - 352, As, Ws);  // splits 6..9
    }
}
__global__ __launch_bounds__(256) void prep_kernel(const u32* h0r,
        const void* wm, u16* BTwm,
        const void* x, const void* w1, const void* pb1, const void* w2, const void* pb2,
        u16* Ab0, const void* h0p, const void* whh0, const void* h1p, const void* whh1,
        float* GS) {
    __shared__ float As[64][66];
    __shared__ float Ws[64][64];
    if (sniff_is_f32(h0r))
        prep_impl<float>((const float*)wm, BTwm, (const float*)x,
                         (const float*)w1, (const float*)pb1, (const float*)w2, (const float*)pb2,
                         Ab0, (const float*)h0p, (const float*)whh0, (const float*)h1p,
                         (const float*)whh1, GS, As, Ws);
    else
        prep_impl<bf16>((const bf16*)wm, BTwm, (const bf16*)x,
                        (const bf16*)w1, (const bf16*)pb1, (const bf16*)w2, (const bf16*)pb2,
                        Ab0, (const bf16*)h0p, (const bf16*)whh0, (const bf16*)h1p,
                        (const bf16*)whh1, GS, As, Ws);
}

// ============== L1: fused ctx + Mproj, DEPTH-2 pipelined, reg B-frags ========
// grid (8, 64), 512 thr = 8 waves. Block = 128 t-rows (2 tiles x 2 c-phases =
// 4 steps, fully unrolled, explicit sequence). TWO register staging sets:
// step s writes set(s&1); sets for s+1 AND s+2 stay in flight across barriers
// and a full compute phase. Wave w owns at-tile w (16 B-frags, loaded once).
// ctx-FMA runs in the write phase straight from staged regs.
template<typename T>
__device__ void ctxproj_impl(const T* mem, const T* w, const u16* BTwm,
                             float* CTXP, u16* Mproj, u16* Alds, float* shw) {
    int tid = threadIdx.x;
    int t0 = blockIdx.x * 128, b = blockIdx.y;
    if (tid < 128) shw[tid] = (t0 + tid < T_) ? ldv(w, (size_t)b * T_ + t0 + tid) : 0.f;
    int L = tid & 63;
    int m = L & 15, q16 = L >> 4;
    int wat = tid >> 6;                 // wave's at-tile (0..7)
    int rg = tid >> 5, cg = tid & 31;

    bf8_t bw[16];
    #pragma unroll
    for (int kc = 0; kc < 16; ++kc)
        bw[kc] = *(const bf8_t*)(BTwm + ((size_t)(wat * 16 + kc) * 64 + L) * 8);

    f4_t acc[4];
    #pragma unroll
    for (int mt = 0; mt < 4; ++mt) acc[mt] = (f4_t){0.f, 0.f, 0.f, 0.f};
    float cacc[16] = {};
    uint4  stbA[4], stbB[4];       // bf16 raw staging (two sets)
    float4 stfA[8], stfB[8];       // f32 raw staging (two sets)

#define LOADSTEP(S, STB, STF) do {                                               \
        const int tt_ = (S) >> 1, ph_ = (S) & 1;                                 \
        _Pragma("unroll")                                                        \
        for (int rr = 0; rr < 4; ++rr) {                                         \
            int i = rr * 512 + tid;                                              \
            int row = i >> 5, c16 = i & 31;                                      \
            int t = t0 + tt_ * 64 + row;                                         \
            size_t base = (size_t)(b * T_ + ((t < T_) ? t : 0)) * DC_ + ph_ * 256 + c16 * 8; \
            if constexpr (sizeof(T) == 2) {                                      \
                STB[rr] = (t < T_) ? *(const uint4*)((const u16*)mem + base)     \
                                   : make_uint4(0u, 0u, 0u, 0u);                 \
            } else {                                                             \
                if (t < T_) { STF[2*rr]   = *(const float4*)(mem + base);        \
                              STF[2*rr+1] = *(const float4*)(mem + base + 4); }  \
                else { STF[2*rr] = make_float4(0.f,0.f,0.f,0.f);                 \
                       STF[2*rr+1] = make_float4(0.f,0.f,0.f,0.f); }             \
            }                                                                    \
        }                                                                        \
    } while (0)

#define WRITESTEP(TT, PH, STB, STF) do {                                         \
        _Pragma("unroll")                                                        \
        for (int rr = 0; rr < 4; ++rr) {                                         \
            int i = rr * 512 + tid;                                              \
            int row = i >> 5, c16 = i & 31;                                      \
            float wvv = shw[(TT) * 64 + row];                                    \
            uint4 v;                                                             \
            if constexpr (sizeof(T) == 2) {                                      \
                v = STB[rr];                                                     \
                float f0 = __uint_as_float(v.x << 16), f1 = __uint_as_float(v.x & 0xffff0000u); \
                float f2 = __uint_as_float(v.y << 16), f3 = __uint_as_float(v.y & 0xffff0000u); \
                float f4 = __uint_as_float(v.z << 16), f5 = __uint_as_float(v.z & 0xffff0000u); \
                float f6 = __uint_as_float(v.w << 16), f7 = __uint_as_float(v.w & 0xffff0000u); \
                cacc[(PH)*8+0] = fmaf(wvv, f0, cacc[(PH)*8+0]); cacc[(PH)*8+1] = fmaf(wvv, f1, cacc[(PH)*8+1]); \
                cacc[(PH)*8+2] = fmaf(wvv, f2, cacc[(PH)*8+2]); cacc[(PH)*8+3] = fmaf(wvv, f3, cacc[(PH)*8+3]); \
                cacc[(PH)*8+4] = fmaf(wvv, f4, cacc[(PH)*8+4]); cacc[(PH)*8+5] = fmaf(wvv, f5, cacc[(PH)*8+5]); \
                cacc[(PH)*8+6] = fmaf(wvv, f6, cacc[(PH)*8+6]); cacc[(PH)*8+7] = fmaf(wvv, f7, cacc[(PH)*8+7]); \
            } else {                                                             \
                float4 a = STF[2*rr], bb = STF[2*rr+1];                          \
                cacc[(PH)*8+0] = fmaf(wvv, a.x,  cacc[(PH)*8+0]); cacc[(PH)*8+1] = fmaf(wvv, a.y,  cacc[(PH)*8+1]); \
                cacc[(PH)*8+2] = fmaf(wvv, a.z,  cacc[(PH)*8+2]); cacc[(PH)*8+3] = fmaf(wvv, a.w,  cacc[(PH)*8+3]); \
                cacc[(PH)*8+4] = fmaf(wvv, bb.x, cacc[(PH)*8+4]); cacc[(PH)*8+5] = fmaf(wvv, bb.y, cacc[(PH)*8+5]); \
                cacc[(PH)*8+6] = fmaf(wvv, bb.z, cacc[(PH)*8+6]); cacc[(PH)*8+7] = fmaf(wvv, bb.w, cacc[(PH)*8+7]); \
                v.x = (u32)f2bu(a.x)  | ((u32)f2bu(a.y)  << 16);                 \
                v.y = (u32)f2bu(a.z)  | ((u32)f2bu(a.w)  << 16);                 \
                v.z = (u32)f2bu(bb.x) | ((u32)f2bu(bb.y) << 16);                 \
                v.w = (u32)f2bu(bb.z) | ((u32)f2bu(bb.w) << 16);                 \
            }                                                                    \
            *(uint4*)(Alds + row * 264 + c16 * 8) = v;                           \
        }                                                                        \
    } while (0)

#define COMPUTESTEP(PH) do {                                                     \
        _Pragma("unroll")                                                        \
        for (int kcl = 0; kcl < 8; ++kcl) {                                      \
            const int kc = (PH) * 8 + kcl;                                       \
            _Pragma("unroll")                                                    \
            for (int mt = 0; mt < 4; ++mt) {                                     \
                bf8_t af = *(const bf8_t*)(Alds + (mt * 16 + m) * 264 + kcl * 32 + q16 * 8); \
                acc[mt] = __builtin_amdgcn_mfma_f32_16x16x32_bf16(af, bw[kc], acc[mt], 0, 0, 0); \
            }                                                                    \
        }                                                                        \
    } while (0)

#define MPROJSTORE(TT) do {                                                      \
        _Pragma("unroll")                                                        \
        for (int mt = 0; mt < 4; ++mt) {                                         \
            _Pragma("unroll")                                                    \
            for (int r = 0; r < 4; ++r) {                                        \
                int trow = t0 + (TT) * 64 + mt * 16 + q16 * 4 + r;               \
                if (trow < T_)                                                   \
                    Mproj[(size_t)(b * T_ + trow) * DA_ + wat * 16 + m] = f2bu(acc[mt][r]); \
            }                                                                    \
            acc[mt] = (f4_t){0.f, 0.f, 0.f, 0.f};                                \
        }                                                                        \
    } while (0)

    LOADSTEP(0, stbA, stfA);
    LOADSTEP(1, stbB, stfB);
    // step 0 (tile 0, phase 0)
    __syncthreads();                       // shw ready
    WRITESTEP(0, 0, stbA, stfA);
    __syncthreads();
    LOADSTEP(2, stbA, stfA);
    COMPUTESTEP(0);
    // step 1 (tile 0, phase 1)
    __syncthreads();
    WRITESTEP(0, 1, stbB, stfB);
    __syncthreads();
    LOADSTEP(3, stbB, stfB);
    COMPUTESTEP(1);
    MPROJSTORE(0);
    // step 2 (tile 1, phase 0)
    __syncthreads();
    WRITESTEP(1, 0, stbA, stfA);
    __syncthreads();
    COMPUTESTEP(0);
    // step 3 (tile 1, phase 1)
    __syncthreads();
    WRITESTEP(1, 1, stbB, stfB);
    __syncthreads();
    COMPUTESTEP(1);
    MPROJSTORE(1);
#undef LOADSTEP
#undef WRITESTEP
#undef COMPUTESTEP
#undef MPROJSTORE
    // ctx partial reduce through reused Alds -> CTXP[chunk][b][c]
    __syncthreads();
    float* part = (float*)Alds;   // 16 groups x 512 cols = 32 KB (fits 33 KB)
    #pragma unroll
    for (int ph = 0; ph < 2; ++ph)
        #pragma unroll
        for (int j = 0; j < 8; ++j)
            part[rg * 512 + ph * 256 + cg * 8 + j] = cacc[ph * 8 + j];
    __syncthreads();
    int c = tid;                  // 0..511
    float s = 0.f;
    #pragma unroll
    for (int gg = 0; gg < 16; ++gg) s += part[gg * 512 + c];
    CTXP[((size_t)blockIdx.x * 64 + b) * DC_ + c] = s;
}
__global__ __launch_bounds__(512, 1) void ctxproj_bf16_kernel(const u32* h0r,
        const void* mem, const void* w, const u16* BTwm, float* CTXP, u16* Mproj) {
    __shared__ __align__(16) u16 Alds[64 * 264];
    __shared__ float shw[128];
    if (sniff_is_f32(h0r)) return;
    ctxproj_impl<bf16>((const bf16*)mem, (const bf16*)w, BTwm, CTXP, Mproj, Alds, shw);
}
__global__ __launch_bounds__(512, 1) void ctxproj_f32_kernel(const u32* h0r,
        const void* mem, const void* w, const u16* BTwm, float* CTXP, u16* Mproj) {
    __shared__ __align__(16) u16 Alds[64 * 264];
    __shared__ float shw[128];
    if (!sniff_is_f32(h0r)) return;
    ctxproj_impl<float>((const float*)mem, (const float*)w, BTwm, CTXP, Mproj, Alds, shw);
}

// ============== L2: pack0 = ctx reduce + ctx packing + QP zero + xdec tail ===
template<typename T>
__device__ void pack0_impl(const float* CTXP, u16* Ab0, u16* Ab1, float* QPf, T* out) {
    int b = blockIdx.x, tid = threadIdx.x;
    T* ctxout = out + O_CTX;
    T* xdec = out + O_XDEC;
    if (tid < 128) QPf[(size_t)b * DA_ + tid] = 0.f;
    for (int c = tid; c < DC_; c += 256) {
        float s = 0.f;
        #pragma unroll
        for (int t = 0; t < 8; ++t) s += CTXP[((size_t)t * 64 + b) * DC_ + c];
        u16 bv = f2bu(s);
        Ab0[(size_t)b * 1664 + 128 + c] = bv;
        Ab1[(size_t)b * 2560 + 1024 + c] = bv;
        stv(ctxout, (size_t)b * DC_ + c, s);
        stv(xdec, (size_t)b * 2560 + 2048 + c, 0.f);
    }
}
__global__ __launch_bounds__(256) void pack0_kernel(const u32* h0r, const float* CTXP,
        u16* Ab0, u16* Ab1, float* QPf, void* out) {
    if (sniff_is_f32(h0r))
        pack0_impl<float>(CTXP, Ab0, Ab1, QPf, (float*)out);
    else
        pack0_impl<bf16>(CTXP, Ab0, Ab1, QPf, (bf16*)out);
}

// ============== L3/L5: LSTM gate GEMM rest-part (BK=64, T14 reg-prefetch) ====
// A from packed bf16 Abuf (stride K), rows [0, L12) -> always Wih.
template<typename T>
__device__ void gemm_impl(const u16* Abuf, int K, int L12, const T* Wih, const T* Whh,
                          float* Gs, int nchunks, float (*As)[66], float (*Ws)[64]) {
    int tid = threadIdx.x;
    int n0b = blockIdx.x * 64;
    int kbase = blockIdx.y * (nchunks * 64);
    int cx = tid & 15, ry = tid >> 4;
    int b0 = ry * 4, n0 = cx * 4;
    int a_bb = tid >> 2, a_k16 = (tid & 3) * 16;
    int w_k  = tid >> 2, w_n16 = (tid & 3) * 16;
    float acc[4][4] = {};
    float va[16], vw[16];
#define GLOAD(CH) do {                                                          \
        int k0 = kbase + (CH) * 64;                                             \
        ld8f_bits(Abuf, (size_t)a_bb * K + k0 + a_k16, va);                     \
        ld8f_bits(Abuf, (size_t)a_bb * K + k0 + a_k16 + 8, va + 8);             \
        int kg = k0 + w_k;                                                      \
        const T* wr = (kg < L12) ? (Wih + (size_t)kg * G4) : (Whh + (size_t)(kg - L12) * G4); \
        ld8f(wr, n0b + w_n16, vw);                                              \
        ld8f(wr, n0b + w_n16 + 8, vw + 8);                                      \
    } while (0)
    GLOAD(0);
    for (int ch = 0; ch < nchunks; ++ch) {
        __syncthreads();
        #pragma unroll
        for (int j = 0; j < 16; ++j) As[a_bb][a_k16 + j] = va[j];
        #pragma unroll
        for (int j = 0; j < 16; ++j) Ws[w_k][w_n16 + j] = vw[j];
        __syncthreads();
        if (ch + 1 < nchunks) GLOAD(ch + 1);
        #pragma unroll
        for (int kk = 0; kk < 64; kk += 2) {
            float2 av[4];
            #pragma unroll
            for (int r = 0; r < 4; ++r) av[r] = *(const float2*)&As[b0 + r][kk];
            float4 w0 = *(const float4*)&Ws[kk][n0];
            float4 w1 = *(const float4*)&Ws[kk + 1][n0];
            #pragma unroll
            for (int r = 0; r < 4; ++r) {
                acc[r][0] = fmaf(av[r].x, w0.x, acc[r][0]); acc[r][0] = fmaf(av[r].y, w1.x, acc[r][0]);
                acc[r][1] = fmaf(av[r].x, w0.y, acc[r][1]); acc[r][1] = fmaf(av[r].y, w1.y, acc[r][1]);
                acc[r][2] = fmaf(av[r].x, w0.z, acc[r][2]); acc[r][2] = fmaf(av[r].y, w1.z, acc[r][2]);
                acc[r][3] = fmaf(av[r].x, w0.w, acc[r][3]); acc[r][3] = fmaf(av[r].y, w1.w, acc[r][3]);
            }
        }
    }
#undef GLOAD
    float* outp = Gs + (size_t)blockIdx.y * (64 * G4);
    #pragma unroll
    for (int r = 0; r < 4; ++r)
        *(float4*)&outp[(size_t)(b0 + r) * G4 + n0b + n0] =
            make_float4(acc[r][0], acc[r][1], acc[r][2], acc[r][3]);
}
__global__ __launch_bounds__(256) void gemm_kernel(const u32* h0r, const u16* Abuf,
        int K, int L12, const void* Wih, const void* Whh, float* Gs, int nchunks) {
    __shared__ float As[64][66];
    __shared__ float Ws[64][64];
    if (sniff_is_f32(h0r))
        gemm_impl<float>(Abuf, K, L12, (const float*)Wih, (const float*)Whh, Gs, nchunks, As, Ws);
    else
        gemm_impl<bf16>(Abuf, K, L12, (const bf16*)Wih, (const bf16*)Whh, Gs, nchunks, As, Ws);
}

// ============== L4/L6: split-reduce + gates + zoneout + fused q-partial ======
template<typename T>
__device__ void gate_impl(const float* Gs, int nsplit, const T* bias, const T* hprev,
                          const T* cprev, const T* wq, int qrow0, float* QPf,
                          T* out, int ho_off, int co_off, int xoff, u16* Ab1,
                          float* hos, float* sarr) {
    int tid = threadIdx.x;
    int idx = blockIdx.x * 256 + tid;             // [0, 65536)
    int b = idx >> 10, u = idx & 1023;
    int u0 = (blockIdx.x & 3) * 256;
    float gi = ldv(bias, u);
    float gf = ldv(bias, 1024 + u);
    float gg = ldv(bias, 2048 + u);
    float go = ldv(bias, 3072 + u);
    for (int s = 0; s < nsplit; ++s) {
        const float* g = Gs + (size_t)s * (64 * G4) + (size_t)b * G4;
        gi += g[u]; gf += g[1024 + u]; gg += g[2048 + u]; go += g[3072 + u];
    }
    float c = ldv(cprev, idx), h = ldv(hprev, idx);
    float si = 1.f / (1.f + expf(-gi));
    float sf = 1.f / (1.f + expf(-gf));
    float so = 1.f / (1.f + expf(-go));
    float cn = sf * c + si * tanhf(gg);
    float hn = so * tanhf(cn);
    float ho = 0.9f * hn + 0.1f * h;
    float co = 0.9f * cn + 0.1f * c;
    stv(out + ho_off, idx, ho);
    stv(out + co_off, idx, co);
    stv(out + O_XDEC, (size_t)b * 2560 + xoff + u, ho);
    if (Ab1 != nullptr) Ab1[(size_t)b * 2560 + u] = f2bu(ho);
    // fused q-partial: q[b,a] += sum_u ho[u] * wq[qrow0+u0+u][a]
    hos[tid] = ho;
    __syncthreads();
    int a = tid & 127, half = tid >> 7;
    float s = 0.f;
    #pragma unroll 8
    for (int j = 0; j < 128; ++j)
        s = fmaf(hos[half * 128 + j], ldv(wq, (size_t)(qrow0 + u0 + half * 128 + j) * DA_ + a), s);
    sarr[tid] = s;
    __syncthreads();
    if (tid < 128) atomicAdd(&QPf[(size_t)b * DA_ + tid], sarr[tid] + sarr[128 + tid]);
}
__global__ __launch_bounds__(256) void gate_kernel(const u32* h0r, const float* Gs, int nsplit,
        const void* bias, const void* hprev, const void* cprev, const void* wq, int qrow0,
        float* QPf, void* out, int ho_off, int co_off, int xoff, u16* Ab1) {
    __shared__ float hos[256];
    __shared__ float sarr[256];
    if (sniff_is_f32(h0r))
        gate_impl<float>(Gs, nsplit, (const float*)bias, (const float*)hprev, (const float*)cprev,
                         (const float*)wq, qrow0, QPf, (float*)out, ho_off, co_off, xoff, Ab1, hos, sarr);
    else
        gate_impl<bf16>(Gs, nsplit, (const bf16*)bias, (const bf16*)hprev, (const bf16*)cprev,
                        (const bf16*)wq, qrow0, QPf, (bf16*)out, ho_off, co_off, xoff, Ab1, hos, sarr);
}

// ============== L8: attention epilogue (tanh-dot-sigmoid) + fused wnew =======
template<typename T>
__device__ void attn_impl(const u16* Mproj, const float* QPf, const T* ab, const T* av,
                          const T* w, T* out, float* qa, float* avl, float* psh) {
    int tid = threadIdx.x;
    int t0 = blockIdx.x * 64, b = blockIdx.y;
    T* wout = out + O_WN;
    if (tid < DA_) {
        qa[tid]  = ldv(ab, tid) + QPf[(size_t)b * DA_ + tid];
        avl[tid] = ldv(av, tid);
    }
    __syncthreads();
    int quad = tid & 3, r = tid >> 2;   // 4 threads per row, 32 a each
    #pragma unroll
    for (int rbase = 0; rbase < 2; ++rbase) {
        int rrow = (rbase == 0) ? r : 64;          // row 64 handled by r==0 quads
        bool act = (rbase == 0) || (r == 0);
        int t = t0 - 1 + rrow;
        float e = 0.f;
        if (act && t >= 0 && t < T_) {
            #pragma unroll
            for (int a8 = 0; a8 < 4; ++a8) {
                float v[8];
                ld8f_bits(Mproj, (size_t)(b * T_ + t) * DA_ + quad * 32 + a8 * 8, v);
                #pragma unroll
                for (int j = 0; j < 8; ++j) {
                    int a = quad * 32 + a8 * 8 + j;
                    e = fmaf(avl[a], tanhf(qa[a] + v[j]), e);
                }
            }
        }
        e += __shfl_xor(e, 1);
        e += __shfl_xor(e, 2);
        if (act && quad == 0 && t >= 0 && t < T_) psh[rrow] = 1.f / (1.f + expf(-e));
    }
    __syncthreads();
    if (tid < 64) {
        int t = t0 + tid;
        if (t < T_) {
            float val = ldv(w, (size_t)b * T_ + t) * psh[tid + 1];
            if (t > 0) val = fmaf(ldv(w, (size_t)b * T_ + t - 1), 1.f - psh[tid], val);
            stv(wout, (size_t)b * T_ + t, val);
        }
    }
}
__global__ __launch_bounds__(256) void attn_kernel(const u32* h0r, const u16* Mproj,
        const float* QPf, const void* ab, const void* av, const void* w, void* out) {
    __shared__ float qa[DA_];
    __shared__ float avl[DA_];
    __shared__ float psh[66];
    if (sniff_is_f32(h0r))
        attn_impl<float>(Mproj, QPf, (const float*)ab, (const float*)av, (const float*)w,
                         (float*)out, qa, avl, psh);
    else
        attn_impl<bf16>(Mproj, QPf, (const bf16*)ab, (const bf16*)av, (const bf16*)w,
                        (bf16*)out, qa, avl, psh);
}

// ---------------- launch -----------------------------------------------------
extern "C" void kernel_launch(void* const* d_in, const int* in_sizes, int n_in,
                              void* d_out, int out_size, void* d_ws, size_t ws_size,
                              hipStream_t stream) {
    (void)in_sizes; (void)n_in; (void)out_size; (void)ws_size;

    // workspace layout (f32 units). Total ~37 MiB.
    float* wsf   = (float*)d_ws;
    float* GS    = wsf;                        // 16 x SPLIT (13 used: L0 h 0-3, L0 rest 4-5, L1 h 6-9, L1 rest 10-12)
    float* CTXP  = wsf + 4194304;              // 8 x 64 x 512 ctx partials
    float* QPf   = wsf + 4718592;              // 64 x 128 accumulated q
    u16*   MPROJ = (u16*)(wsf + 4784128);      // 64 x 1000 x 128 bf16
    u16*   AB0   = (u16*)(wsf + 8880128);      // 64 x 1664 bf16 (cols 0..640 used)
    u16*   AB1   = (u16*)(wsf + 8933376);      // 64 x 2560 bf16 (cols 0..1536 used)
    u16*   BTWM  = (u16*)(wsf + 9080832);      // 65536 bf16

    const u32* H0R = (const u32*)d_in[2];

    // L0: btprep + prenet + h-state GEMMs (whh0/whh1 streams, off critical path)
    prep_kernel<<<608, 256, 0, stream>>>(H0R, d_in[19], BTWM,
                                         d_in[0], d_in[8], d_in[9], d_in[10], d_in[11], AB0,
                                         d_in[2], d_in[13], d_in[4], d_in[16], GS);
    // L1: fused ctx + Mproj, depth-2 pipelined (dtype-split kernels)
    ctxproj_bf16_kernel<<<dim3(8, 64), 512, 0, stream>>>(H0R, d_in[6], d_in[1], BTWM, CTXP, MPROJ);
    ctxproj_f32_kernel <<<dim3(8, 64), 512, 0, stream>>>(H0R, d_in[6], d_in[1], BTWM, CTXP, MPROJ);
    // L2: ctx reduce + packing + QP zero + xdec tail zeros
    pack0_kernel<<<64, 256, 0, stream>>>(H0R, CTXP, AB0, AB1, QPf, d_out);
    // L3/L4: LSTM layer 0 rest (K-rows 0..640 = xpre+ctx, wih0; 2 splits x 5 chunks)
    gemm_kernel<<<dim3(64, 2), 256, 0, stream>>>(H0R, AB0, 1664, 640, d_in[12], d_in[12],
                                                 GS + (size_t)4 * SPLIT, 5);
    gate_kernel<<<256, 256, 0, stream>>>(H0R, GS, 6, d_in[14], d_in[2], d_in[3],
                                         d_in[18], 0, QPf, d_out, O_H0, O_C0, 0, AB1);
    // L5/L6: LSTM layer 1 rest (K-rows 0..1536 = h0n+ctx, wih1; 3 splits x 8 chunks)
    gemm_kernel<<<dim3(64, 3), 256, 0, stream>>>(H0R, AB1, 2560, 1536, d_in[15], d_in[15],
                                                 GS + (size_t)10 * SPLIT, 8);
    gate_kernel<<<256, 256, 0, stream>>>(H0R, GS + (size_t)6 * SPLIT, 7, d_in[17], d_in[4], d_in[5],
                                         d_in[18], 1024, QPf, d_out, O_H1, O_C1, 1024, (u16*)nullptr);
    // L8: p = sigmoid(v . tanh(q + Mproj)) fused with w_new
    attn_kernel<<<dim3(16, 64), 256, 0, stream>>>(H0R, MPROJ, QPf, d_in[20], d_in[21], d_in[1], d_out);
}

// Round 10
// 387.476 us; speedup vs baseline: 1.0033x; 1.0033x over previous
//
#include <hip/hip_runtime.h>
#include <hip/hip_bf16.h>
#include <stdint.h>

// Problem constants
#define B_  64
#define T_  1000
#define DC_ 512
#define DM_ 80
#define DP_ 128
#define DH_ 128
#define DA_ 128
#define DRN 1024
#define G4  4096
#define SPLIT 262144              // one gate split buffer: 64 x 4096 f32

typedef __hip_bfloat16 bf16;
typedef unsigned short u16;
typedef unsigned int   u32;

// MFMA fragment types
typedef short bf8_t __attribute__((ext_vector_type(8)));
typedef float f4_t  __attribute__((ext_vector_type(4)));

// out element offsets: x_dec, ctx, w_new, h0n, c0n, h1n, c1n
#define O_XDEC 0
#define O_CTX  163840
#define O_WN   196608
#define O_H0   260608
#define O_C0   326144
#define O_H1   391680
#define O_C1   457216

__device__ __forceinline__ float b2f(bf16 v) { return __bfloat162float(v); }
__device__ __forceinline__ bf16  f2b(float v) { return __float2bfloat16(v); }
__device__ __forceinline__ u16   f2bu(float v) { return __builtin_bit_cast(u16, __float2bfloat16(v)); }

__device__ __forceinline__ float ldv(const float* p, size_t i) { return p[i]; }
__device__ __forceinline__ float ldv(const bf16*  p, size_t i) { return b2f(p[i]); }
__device__ __forceinline__ void  stv(float* p, size_t i, float v) { p[i] = v; }
__device__ __forceinline__ void  stv(bf16*  p, size_t i, float v) { p[i] = f2b(v); }

// load 8 consecutive elems as f32
template<typename T>
__device__ __forceinline__ void ld8f(const T* p, size_t i, float* o) {
    if constexpr (sizeof(T) == 2) {
        uint4 u = *(const uint4*)((const u16*)p + i);
        o[0] = __uint_as_float(u.x << 16); o[1] = __uint_as_float(u.x & 0xffff0000u);
        o[2] = __uint_as_float(u.y << 16); o[3] = __uint_as_float(u.y & 0xffff0000u);
        o[4] = __uint_as_float(u.z << 16); o[5] = __uint_as_float(u.z & 0xffff0000u);
        o[6] = __uint_as_float(u.w << 16); o[7] = __uint_as_float(u.w & 0xffff0000u);
    } else {
        float4 a = *(const float4*)(p + i);
        float4 b = *(const float4*)(p + i + 4);
        o[0]=a.x; o[1]=a.y; o[2]=a.z; o[3]=a.w; o[4]=b.x; o[5]=b.y; o[6]=b.z; o[7]=b.w;
    }
}
__device__ __forceinline__ void ld8f_bits(const u16* p, size_t i, float* o) {
    uint4 u = *(const uint4*)(p + i);
    o[0] = __uint_as_float(u.x << 16); o[1] = __uint_as_float(u.x & 0xffff0000u);
    o[2] = __uint_as_float(u.y << 16); o[3] = __uint_as_float(u.y & 0xffff0000u);
    o[4] = __uint_as_float(u.z << 16); o[5] = __uint_as_float(u.z & 0xffff0000u);
    o[6] = __uint_as_float(u.w << 16); o[7] = __uint_as_float(u.w & 0xffff0000u);
}

// ---------------- per-block dtype sniff (proven heuristic; wave-uniform) -----
__device__ __forceinline__ bool sniff_is_f32(const u32* h0raw) {
    int lane = threadIdx.x & 63;
    int c = 0;
    #pragma unroll
    for (int i = 0; i < 4; ++i) {
        u32 e = (h0raw[lane * 4 + i] >> 7) & 0xFF;
        c += (e >= 100 && e <= 126) ? 1 : 0;
    }
    #pragma unroll
    for (int s = 1; s < 64; s <<= 1) c += __shfl_xor(c, s);
    return c < 128;
}

// ---------------- Threefry-2x32 (bit-exact vs JAX — do not touch) ------------
__device__ __forceinline__ u32 rotl32(u32 v, int r) { return (v << r) | (v >> (32 - r)); }
__device__ __forceinline__ void threefry2x32(u32 k0, u32 k1, u32 x0, u32 x1, u32& y0, u32& y1) {
    u32 ks2 = k0 ^ k1 ^ 0x1BD11BDAu;
    x0 += k0; x1 += k1;
#define TF_R(r) { x0 += x1; x1 = rotl32(x1, r); x1 ^= x0; }
    TF_R(13) TF_R(15) TF_R(26) TF_R(6)
    x0 += k1; x1 += ks2 + 1u;
    TF_R(17) TF_R(29) TF_R(16) TF_R(24)
    x0 += ks2; x1 += k0 + 2u;
    TF_R(13) TF_R(15) TF_R(26) TF_R(6)
    x0 += k0; x1 += k1 + 3u;
    TF_R(17) TF_R(29) TF_R(16) TF_R(24)
    x0 += k1; x1 += ks2 + 4u;
    TF_R(13) TF_R(15) TF_R(26) TF_R(6)
    x0 += ks2; x1 += k0 + 5u;
#undef TF_R
    y0 = x0; y1 = x1;
}
__device__ __forceinline__ float dropout_mask(int which, int j) {
    u32 dk0, dk1, b1, b2;
    threefry2x32(0u, 42u, 0u, (u32)which, dk0, dk1);
    threefry2x32(dk0, dk1, 0u, (u32)j, b1, b2);
    u32 bits = b1 ^ b2;
    float u = __uint_as_float((bits >> 9) | 0x3f800000u) - 1.0f;
    return (u < 0.5f) ? 2.0f : 0.0f;
}

// ============== L0: prep = btprep(0..31) + prenet(32..95) + h-GEMMs(96..607) =
// h-GEMM: C_split = hprev[64][1024] @ Whh[1024][4096].
// unit u: n-tile = u&63, split = u>>6 (4 splits x 4 chunks of 64 k-rows).
template<typename T>
__device__ void hgemm_impl(const T* hprev, const T* Whh, float* GsL, int unit,
                           float (*As)[66], float (*Ws)[64]) {
    int tid = threadIdx.x;
    int n0b = (unit & 63) * 64;
    int split = unit >> 6;              // 0..3
    int kbase = split * 256;
    int cx = tid & 15, ry = tid >> 4;
    int b0 = ry * 4, n0 = cx * 4;
    int a_bb = tid >> 2, a_k16 = (tid & 3) * 16;
    int w_k  = tid >> 2, w_n16 = (tid & 3) * 16;
    float acc[4][4] = {};
    float va[16], vw[16];
#define HGLOAD(CH) do {                                                         \
        int k0 = kbase + (CH) * 64;                                             \
        ld8f(hprev, (size_t)a_bb * DRN + k0 + a_k16, va);                       \
        ld8f(hprev, (size_t)a_bb * DRN + k0 + a_k16 + 8, va + 8);               \
        const T* wr = Whh + (size_t)(k0 + w_k) * G4;                            \
        ld8f(wr, n0b + w_n16, vw);                                              \
        ld8f(wr, n0b + w_n16 + 8, vw + 8);                                      \
    } while (0)
    HGLOAD(0);
    for (int ch = 0; ch < 4; ++ch) {
        __syncthreads();
        #pragma unroll
        for (int j = 0; j < 16; ++j) As[a_bb][a_k16 + j] = va[j];
        #pragma unroll
        for (int j = 0; j < 16; ++j) Ws[w_k][w_n16 + j] = vw[j];
        __syncthreads();
        if (ch + 1 < 4) HGLOAD(ch + 1);
        #pragma unroll
        for (int kk = 0; kk < 64; kk += 2) {
            float2 av[4];
            #pragma unroll
            for (int r = 0; r < 4; ++r) av[r] = *(const float2*)&As[b0 + r][kk];
            float4 w0 = *(const float4*)&Ws[kk][n0];
            float4 w1 = *(const float4*)&Ws[kk + 1][n0];
            #pragma unroll
            for (int r = 0; r < 4; ++r) {
                acc[r][0] = fmaf(av[r].x, w0.x, acc[r][0]); acc[r][0] = fmaf(av[r].y, w1.x, acc[r][0]);
                acc[r][1] = fmaf(av[r].x, w0.y, acc[r][1]); acc[r][1] = fmaf(av[r].y, w1.y, acc[r][1]);
                acc[r][2] = fmaf(av[r].x, w0.z, acc[r][2]); acc[r][2] = fmaf(av[r].y, w1.z, acc[r][2]);
                acc[r][3] = fmaf(av[r].x, w0.w, acc[r][3]); acc[r][3] = fmaf(av[r].y, w1.w, acc[r][3]);
            }
        }
    }
#undef HGLOAD
    float* outp = GsL + (size_t)split * (64 * G4);
    #pragma unroll
    for (int r = 0; r < 4; ++r)
        *(float4*)&outp[(size_t)(b0 + r) * G4 + n0b + n0] =
            make_float4(acc[r][0], acc[r][1], acc[r][2], acc[r][3]);
}

template<typename T>
__device__ void prep_impl(const T* wm, u16* BTwm,
                          const T* x, const T* w1, const T* pb1, const T* w2, const T* pb2,
                          u16* Ab0, const T* h0p, const T* whh0, const T* h1p, const T* whh1,
                          float* GS, float (*As)[66], float (*Ws)[64]) {
    int bid = blockIdx.x, tid = threadIdx.x;
    if (bid < 32) {
        int gid = bid * 256 + tid;          // < 8192
        int L = gid & 63, kc = (gid >> 6) & 15, at = gid >> 10;
        u16* dst = BTwm + (size_t)gid * 8;
        int col = at * 16 + (L & 15);
        int krow = kc * 32 + (L >> 4) * 8;
        u16 v[8];
        #pragma unroll
        for (int j = 0; j < 8; ++j) v[j] = f2bu(ldv(wm, (size_t)(krow + j) * DA_ + col));
        uint4 pk;
        pk.x = v[0] | ((u32)v[1] << 16); pk.y = v[2] | ((u32)v[3] << 16);
        pk.z = v[4] | ((u32)v[5] << 16); pk.w = v[6] | ((u32)v[7] << 16);
        *(uint4*)dst = pk;
    } else if (bid < 96) {
        int b = bid - 32;
        float* xs = &As[0][0];        // [80]
        float* hs = xs + DM_;         // [128]
        if (tid < DM_) xs[tid] = ldv(x, (size_t)b * DM_ + tid);
        __syncthreads();
        if (tid < DH_) {
            float acc = ldv(pb1, tid);
            #pragma unroll 8
            for (int k = 0; k < DM_; ++k) acc = fmaf(xs[k], ldv(w1, (size_t)k * DH_ + tid), acc);
            acc = fmaxf(acc, 0.f) * dropout_mask(0, b * DH_ + tid);
            hs[tid] = acc;
        }
        __syncthreads();
        if (tid < DP_) {
            float acc2 = ldv(pb2, tid);
            #pragma unroll 8
            for (int k = 0; k < DH_; ++k) acc2 = fmaf(hs[k], ldv(w2, (size_t)k * DP_ + tid), acc2);
            acc2 = fmaxf(acc2, 0.f) * dropout_mask(1, b * DP_ + tid);
            Ab0[(size_t)b * 1664 + tid] = f2bu(acc2);
        }
    } else if (bid < 352) {
        hgemm_impl<T>(h0p, whh0, GS, bid - 96, As, Ws);               // splits 0..3
    } else {
        hgemm_impl<T>(h1p, whh1, GS + (size_t)9 * SPLIT, bid - 352, As, Ws);  // splits 9..12
    }
}
__global__ __launch_bounds__(256) void prep_kernel(const u32* h0r,
        const void* wm, u16* BTwm,
        const void* x, const void* w1, const void* pb1, const void* w2, const void* pb2,
        u16* Ab0, const void* h0p, const void* whh0, const void* h1p, const void* whh1,
        float* GS) {
    __shared__ float As[64][66];
    __shared__ float Ws[64][64];
    if (sniff_is_f32(h0r))
        prep_impl<float>((const float*)wm, BTwm, (const float*)x,
                         (const float*)w1, (const float*)pb1, (const float*)w2, (const float*)pb2,
                         Ab0, (const float*)h0p, (const float*)whh0, (const float*)h1p,
                         (const float*)whh1, GS, As, Ws);
    else
        prep_impl<bf16>((const bf16*)wm, BTwm, (const bf16*)x,
                        (const bf16*)w1, (const bf16*)pb1, (const bf16*)w2, (const bf16*)pb2,
                        Ab0, (const bf16*)h0p, (const bf16*)whh0, (const bf16*)h1p,
                        (const bf16*)whh1, GS, As, Ws);
}

// ============== L1: fused ctx + Mproj, MERGED dtype, convert-at-load =========
// grid (8, 64), 512 thr = 8 waves. Block = 128 t-rows, 4 steps, depth-2
// register staging. Both dtypes stage PACKED BF16 BITS (f32 converts at load;
// ctx accumulates from the bf16-rounded values — err ~1e-4 << 6.7e-3 thresh,
// and ctx feeds the LSTM through bf16 packing anyway). Wave w owns at-tile w
// (16 B-frags, loaded once). ctx-FMA runs in the write phase from staged regs.
template<typename T>
__device__ void ctxproj_impl(const T* mem, const T* w, const u16* BTwm,
                             float* CTXP, u16* Mproj, u16* Alds, float* shw) {
    int tid = threadIdx.x;
    int t0 = blockIdx.x * 128, b = blockIdx.y;
    if (tid < 128) shw[tid] = (t0 + tid < T_) ? ldv(w, (size_t)b * T_ + t0 + tid) : 0.f;
    int L = tid & 63;
    int m = L & 15, q16 = L >> 4;
    int wat = tid >> 6;                 // wave's at-tile (0..7)
    int rg = tid >> 5, cg = tid & 31;

    bf8_t bw[16];
    #pragma unroll
    for (int kc = 0; kc < 16; ++kc)
        bw[kc] = *(const bf8_t*)(BTwm + ((size_t)(wat * 16 + kc) * 64 + L) * 8);

    f4_t acc[4];
    #pragma unroll
    for (int mt = 0; mt < 4; ++mt) acc[mt] = (f4_t){0.f, 0.f, 0.f, 0.f};
    float cacc[16] = {};
    uint4 stbA[4], stbB[4];        // packed bf16 staging (two sets)

#define LOADSTEP(S, STB) do {                                                    \
        const int tt_ = (S) >> 1, ph_ = (S) & 1;                                 \
        _Pragma("unroll")                                                        \
        for (int rr = 0; rr < 4; ++rr) {                                         \
            int i = rr * 512 + tid;                                              \
            int row = i >> 5, c16 = i & 31;                                      \
            int t = t0 + tt_ * 64 + row;                                         \
            size_t base = (size_t)(b * T_ + ((t < T_) ? t : 0)) * DC_ + ph_ * 256 + c16 * 8; \
            if constexpr (sizeof(T) == 2) {                                      \
                STB[rr] = (t < T_) ? *(const uint4*)((const u16*)mem + base)     \
                                   : make_uint4(0u, 0u, 0u, 0u);                 \
            } else {                                                             \
                float4 a = make_float4(0.f,0.f,0.f,0.f), bb = a;                 \
                if (t < T_) { a = *(const float4*)(mem + base);                  \
                              bb = *(const float4*)(mem + base + 4); }           \
                STB[rr].x = (u32)f2bu(a.x)  | ((u32)f2bu(a.y)  << 16);           \
                STB[rr].y = (u32)f2bu(a.z)  | ((u32)f2bu(a.w)  << 16);           \
                STB[rr].z = (u32)f2bu(bb.x) | ((u32)f2bu(bb.y) << 16);           \
                STB[rr].w = (u32)f2bu(bb.z) | ((u32)f2bu(bb.w) << 16);           \
            }                                                                    \
        }                                                                        \
    } while (0)

#define WRITESTEP(TT, PH, STB) do {                                              \
        _Pragma("unroll")                                                        \
        for (int rr = 0; rr < 4; ++rr) {                                         \
            int i = rr * 512 + tid;                                              \
            int row = i >> 5, c16 = i & 31;                                      \
            float wvv = shw[(TT) * 64 + row];                                    \
            uint4 v = STB[rr];                                                   \
            float f0 = __uint_as_float(v.x << 16), f1 = __uint_as_float(v.x & 0xffff0000u); \
            float f2 = __uint_as_float(v.y << 16), f3 = __uint_as_float(v.y & 0xffff0000u); \
            float f4 = __uint_as_float(v.z << 16), f5 = __uint_as_float(v.z & 0xffff0000u); \
            float f6 = __uint_as_float(v.w << 16), f7 = __uint_as_float(v.w & 0xffff0000u); \
            cacc[(PH)*8+0] = fmaf(wvv, f0, cacc[(PH)*8+0]); cacc[(PH)*8+1] = fmaf(wvv, f1, cacc[(PH)*8+1]); \
            cacc[(PH)*8+2] = fmaf(wvv, f2, cacc[(PH)*8+2]); cacc[(PH)*8+3] = fmaf(wvv, f3, cacc[(PH)*8+3]); \
            cacc[(PH)*8+4] = fmaf(wvv, f4, cacc[(PH)*8+4]); cacc[(PH)*8+5] = fmaf(wvv, f5, cacc[(PH)*8+5]); \
            cacc[(PH)*8+6] = fmaf(wvv, f6, cacc[(PH)*8+6]); cacc[(PH)*8+7] = fmaf(wvv, f7, cacc[(PH)*8+7]); \
            *(uint4*)(Alds + row * 264 + c16 * 8) = v;                           \
        }                                                                        \
    } while (0)

#define COMPUTESTEP(PH) do {                                                     \
        _Pragma("unroll")                                                        \
        for (int kcl = 0; kcl < 8; ++kcl) {                                      \
            const int kc = (PH) * 8 + kcl;                                       \
            _Pragma("unroll")                                                    \
            for (int mt = 0; mt < 4; ++mt) {                                     \
                bf8_t af = *(const bf8_t*)(Alds + (mt * 16 + m) * 264 + kcl * 32 + q16 * 8); \
                acc[mt] = __builtin_amdgcn_mfma_f32_16x16x32_bf16(af, bw[kc], acc[mt], 0, 0, 0); \
            }                                                                    \
        }                                                                        \
    } while (0)

#define MPROJSTORE(TT) do {                                                      \
        _Pragma("unroll")                                                        \
        for (int mt = 0; mt < 4; ++mt) {                                         \
            _Pragma("unroll")                                                    \
            for (int r = 0; r < 4; ++r) {                                        \
                int trow = t0 + (TT) * 64 + mt * 16 + q16 * 4 + r;               \
                if (trow < T_)                                                   \
                    Mproj[(size_t)(b * T_ + trow) * DA_ + wat * 16 + m] = f2bu(acc[mt][r]); \
            }                                                                    \
            acc[mt] = (f4_t){0.f, 0.f, 0.f, 0.f};                                \
        }                                                                        \
    } while (0)

    LOADSTEP(0, stbA);
    LOADSTEP(1, stbB);
    // step 0 (tile 0, phase 0)
    __syncthreads();                       // shw ready
    WRITESTEP(0, 0, stbA);
    __syncthreads();
    LOADSTEP(2, stbA);
    COMPUTESTEP(0);
    // step 1 (tile 0, phase 1)
    __syncthreads();
    WRITESTEP(0, 1, stbB);
    __syncthreads();
    LOADSTEP(3, stbB);
    COMPUTESTEP(1);
    MPROJSTORE(0);
    // step 2 (tile 1, phase 0)
    __syncthreads();
    WRITESTEP(1, 0, stbA);
    __syncthreads();
    COMPUTESTEP(0);
    // step 3 (tile 1, phase 1)
    __syncthreads();
    WRITESTEP(1, 1, stbB);
    __syncthreads();
    COMPUTESTEP(1);
    MPROJSTORE(1);
#undef LOADSTEP
#undef WRITESTEP
#undef COMPUTESTEP
#undef MPROJSTORE
    // ctx partial reduce through reused Alds -> CTXP[chunk][b][c]
    __syncthreads();
    float* part = (float*)Alds;   // 16 groups x 512 cols = 32 KB (fits 33 KB)
    #pragma unroll
    for (int ph = 0; ph < 2; ++ph)
        #pragma unroll
        for (int j = 0; j < 8; ++j)
            part[rg * 512 + ph * 256 + cg * 8 + j] = cacc[ph * 8 + j];
    __syncthreads();
    int c = tid;                  // 0..511
    float s = 0.f;
    #pragma unroll
    for (int gg = 0; gg < 16; ++gg) s += part[gg * 512 + c];
    CTXP[((size_t)blockIdx.x * 64 + b) * DC_ + c] = s;
}
__global__ __launch_bounds__(512) void ctxproj_kernel(const u32* h0r,
        const void* mem, const void* w, const u16* BTwm, float* CTXP, u16* Mproj) {
    __shared__ __align__(16) u16 Alds[64 * 264];
    __shared__ float shw[128];
    if (sniff_is_f32(h0r))
        ctxproj_impl<float>((const float*)mem, (const float*)w, BTwm, CTXP, Mproj, Alds, shw);
    else
        ctxproj_impl<bf16>((const bf16*)mem, (const bf16*)w, BTwm, CTXP, Mproj, Alds, shw);
}

// ============== L2: pack0 = ctx reduce + ctx packing + QP zero + xdec tail ===
template<typename T>
__device__ void pack0_impl(const float* CTXP, u16* Ab0, u16* Ab1, float* QPf, T* out) {
    int b = blockIdx.x, tid = threadIdx.x;
    T* ctxout = out + O_CTX;
    T* xdec = out + O_XDEC;
    if (tid < 128) QPf[(size_t)b * DA_ + tid] = 0.f;
    for (int c = tid; c < DC_; c += 256) {
        float s = 0.f;
        #pragma unroll
        for (int t = 0; t < 8; ++t) s += CTXP[((size_t)t * 64 + b) * DC_ + c];
        u16 bv = f2bu(s);
        Ab0[(size_t)b * 1664 + 128 + c] = bv;
        Ab1[(size_t)b * 2560 + 1024 + c] = bv;
        stv(ctxout, (size_t)b * DC_ + c, s);
        stv(xdec, (size_t)b * 2560 + 2048 + c, 0.f);
    }
}
__global__ __launch_bounds__(256) void pack0_kernel(const u32* h0r, const float* CTXP,
        u16* Ab0, u16* Ab1, float* QPf, void* out) {
    if (sniff_is_f32(h0r))
        pack0_impl<float>(CTXP, Ab0, Ab1, QPf, (float*)out);
    else
        pack0_impl<bf16>(CTXP, Ab0, Ab1, QPf, (bf16*)out);
}

// ============== L3/L5: LSTM gate GEMM rest-part (BK=64, T14 reg-prefetch) ====
// A from packed bf16 Abuf (stride K), rows [0, L12) -> always Wih.
template<typename T>
__device__ void gemm_impl(const u16* Abuf, int K, int L12, const T* Wih, const T* Whh,
                          float* Gs, int nchunks, float (*As)[66], float (*Ws)[64]) {
    int tid = threadIdx.x;
    int n0b = blockIdx.x * 64;
    int kbase = blockIdx.y * (nchunks * 64);
    int cx = tid & 15, ry = tid >> 4;
    int b0 = ry * 4, n0 = cx * 4;
    int a_bb = tid >> 2, a_k16 = (tid & 3) * 16;
    int w_k  = tid >> 2, w_n16 = (tid & 3) * 16;
    float acc[4][4] = {};
    float va[16], vw[16];
#define GLOAD(CH) do {                                                          \
        int k0 = kbase + (CH) * 64;                                             \
        ld8f_bits(Abuf, (size_t)a_bb * K + k0 + a_k16, va);                     \
        ld8f_bits(Abuf, (size_t)a_bb * K + k0 + a_k16 + 8, va + 8);             \
        int kg = k0 + w_k;                                                      \
        const T* wr = (kg < L12) ? (Wih + (size_t)kg * G4) : (Whh + (size_t)(kg - L12) * G4); \
        ld8f(wr, n0b + w_n16, vw);                                              \
        ld8f(wr, n0b + w_n16 + 8, vw + 8);                                      \
    } while (0)
    GLOAD(0);
    for (int ch = 0; ch < nchunks; ++ch) {
        __syncthreads();
        #pragma unroll
        for (int j = 0; j < 16; ++j) As[a_bb][a_k16 + j] = va[j];
        #pragma unroll
        for (int j = 0; j < 16; ++j) Ws[w_k][w_n16 + j] = vw[j];
        __syncthreads();
        if (ch + 1 < nchunks) GLOAD(ch + 1);
        #pragma unroll
        for (int kk = 0; kk < 64; kk += 2) {
            float2 av[4];
            #pragma unroll
            for (int r = 0; r < 4; ++r) av[r] = *(const float2*)&As[b0 + r][kk];
            float4 w0 = *(const float4*)&Ws[kk][n0];
            float4 w1 = *(const float4*)&Ws[kk + 1][n0];
            #pragma unroll
            for (int r = 0; r < 4; ++r) {
                acc[r][0] = fmaf(av[r].x, w0.x, acc[r][0]); acc[r][0] = fmaf(av[r].y, w1.x, acc[r][0]);
                acc[r][1] = fmaf(av[r].x, w0.y, acc[r][1]); acc[r][1] = fmaf(av[r].y, w1.y, acc[r][1]);
                acc[r][2] = fmaf(av[r].x, w0.z, acc[r][2]); acc[r][2] = fmaf(av[r].y, w1.z, acc[r][2]);
                acc[r][3] = fmaf(av[r].x, w0.w, acc[r][3]); acc[r][3] = fmaf(av[r].y, w1.w, acc[r][3]);
            }
        }
    }
#undef GLOAD
    float* outp = Gs + (size_t)blockIdx.y * (64 * G4);
    #pragma unroll
    for (int r = 0; r < 4; ++r)
        *(float4*)&outp[(size_t)(b0 + r) * G4 + n0b + n0] =
            make_float4(acc[r][0], acc[r][1], acc[r][2], acc[r][3]);
}
__global__ __launch_bounds__(256) void gemm_kernel(const u32* h0r, const u16* Abuf,
        int K, int L12, const void* Wih, const void* Whh, float* Gs, int nchunks) {
    __shared__ float As[64][66];
    __shared__ float Ws[64][64];
    if (sniff_is_f32(h0r))
        gemm_impl<float>(Abuf, K, L12, (const float*)Wih, (const float*)Whh, Gs, nchunks, As, Ws);
    else
        gemm_impl<bf16>(Abuf, K, L12, (const bf16*)Wih, (const bf16*)Whh, Gs, nchunks, As, Ws);
}

// ============== L4/L6: split-reduce + gates + zoneout + fused q-partial ======
template<typename T>
__device__ void gate_impl(const float* Gs, int nsplit, const T* bias, const T* hprev,
                          const T* cprev, const T* wq, int qrow0, float* QPf,
                          T* out, int ho_off, int co_off, int xoff, u16* Ab1,
                          float* hos, float* sarr) {
    int tid = threadIdx.x;
    int idx = blockIdx.x * 256 + tid;             // [0, 65536)
    int b = idx >> 10, u = idx & 1023;
    int u0 = (blockIdx.x & 3) * 256;
    float gi = ldv(bias, u);
    float gf = ldv(bias, 1024 + u);
    float gg = ldv(bias, 2048 + u);
    float go = ldv(bias, 3072 + u);
    for (int s = 0; s < nsplit; ++s) {
        const float* g = Gs + (size_t)s * (64 * G4) + (size_t)b * G4;
        gi += g[u]; gf += g[1024 + u]; gg += g[2048 + u]; go += g[3072 + u];
    }
    float c = ldv(cprev, idx), h = ldv(hprev, idx);
    float si = 1.f / (1.f + expf(-gi));
    float sf = 1.f / (1.f + expf(-gf));
    float so = 1.f / (1.f + expf(-go));
    float cn = sf * c + si * tanhf(gg);
    float hn = so * tanhf(cn);
    float ho = 0.9f * hn + 0.1f * h;
    float co = 0.9f * cn + 0.1f * c;
    stv(out + ho_off, idx, ho);
    stv(out + co_off, idx, co);
    stv(out + O_XDEC, (size_t)b * 2560 + xoff + u, ho);
    if (Ab1 != nullptr) Ab1[(size_t)b * 2560 + u] = f2bu(ho);
    // fused q-partial: q[b,a] += sum_u ho[u] * wq[qrow0+u0+u][a]
    hos[tid] = ho;
    __syncthreads();
    int a = tid & 127, half = tid >> 7;
    float s = 0.f;
    #pragma unroll 8
    for (int j = 0; j < 128; ++j)
        s = fmaf(hos[half * 128 + j], ldv(wq, (size_t)(qrow0 + u0 + half * 128 + j) * DA_ + a), s);
    sarr[tid] = s;
    __syncthreads();
    if (tid < 128) atomicAdd(&QPf[(size_t)b * DA_ + tid], sarr[tid] + sarr[128 + tid]);
}
__global__ __launch_bounds__(256) void gate_kernel(const u32* h0r, const float* Gs, int nsplit,
        const void* bias, const void* hprev, const void* cprev, const void* wq, int qrow0,
        float* QPf, void* out, int ho_off, int co_off, int xoff, u16* Ab1) {
    __shared__ float hos[256];
    __shared__ float sarr[256];
    if (sniff_is_f32(h0r))
        gate_impl<float>(Gs, nsplit, (const float*)bias, (const float*)hprev, (const float*)cprev,
                         (const float*)wq, qrow0, QPf, (float*)out, ho_off, co_off, xoff, Ab1, hos, sarr);
    else
        gate_impl<bf16>(Gs, nsplit, (const bf16*)bias, (const bf16*)hprev, (const bf16*)cprev,
                        (const bf16*)wq, qrow0, QPf, (bf16*)out, ho_off, co_off, xoff, Ab1, hos, sarr);
}

// ============== L8: attention epilogue (tanh-dot-sigmoid) + fused wnew =======
template<typename T>
__device__ void attn_impl(const u16* Mproj, const float* QPf, const T* ab, const T* av,
                          const T* w, T* out, float* qa, float* avl, float* psh) {
    int tid = threadIdx.x;
    int t0 = blockIdx.x * 64, b = blockIdx.y;
    T* wout = out + O_WN;
    if (tid < DA_) {
        qa[tid]  = ldv(ab, tid) + QPf[(size_t)b * DA_ + tid];
        avl[tid] = ldv(av, tid);
    }
    __syncthreads();
    int quad = tid & 3, r = tid >> 2;   // 4 threads per row, 32 a each
    #pragma unroll
    for (int rbase = 0; rbase < 2; ++rbase) {
        int rrow = (rbase == 0) ? r : 64;          // row 64 handled by r==0 quads
        bool act = (rbase == 0) || (r == 0);
        int t = t0 - 1 + rrow;
        float e = 0.f;
        if (act && t >= 0 && t < T_) {
            #pragma unroll
            for (int a8 = 0; a8 < 4; ++a8) {
                float v[8];
                ld8f_bits(Mproj, (size_t)(b * T_ + t) * DA_ + quad * 32 + a8 * 8, v);
                #pragma unroll
                for (int j = 0; j < 8; ++j) {
                    int a = quad * 32 + a8 * 8 + j;
                    e = fmaf(avl[a], tanhf(qa[a] + v[j]), e);
                }
            }
        }
        e += __shfl_xor(e, 1);
        e += __shfl_xor(e, 2);
        if (act && quad == 0 && t >= 0 && t < T_) psh[rrow] = 1.f / (1.f + expf(-e));
    }
    __syncthreads();
    if (tid < 64) {
        int t = t0 + tid;
        if (t < T_) {
            float val = ldv(w, (size_t)b * T_ + t) * psh[tid + 1];
            if (t > 0) val = fmaf(ldv(w, (size_t)b * T_ + t - 1), 1.f - psh[tid], val);
            stv(wout, (size_t)b * T_ + t, val);
        }
    }
}
__global__ __launch_bounds__(256) void attn_kernel(const u32* h0r, const u16* Mproj,
        const float* QPf, const void* ab, const void* av, const void* w, void* out) {
    __shared__ float qa[DA_];
    __shared__ float avl[DA_];
    __shared__ float psh[66];
    if (sniff_is_f32(h0r))
        attn_impl<float>(Mproj, QPf, (const float*)ab, (const float*)av, (const float*)w,
                         (float*)out, qa, avl, psh);
    else
        attn_impl<bf16>(Mproj, QPf, (const bf16*)ab, (const bf16*)av, (const bf16*)w,
                        (bf16*)out, qa, avl, psh);
}

// ---------------- launch -----------------------------------------------------
extern "C" void kernel_launch(void* const* d_in, const int* in_sizes, int n_in,
                              void* d_out, int out_size, void* d_ws, size_t ws_size,
                              hipStream_t stream) {
    (void)in_sizes; (void)n_in; (void)out_size; (void)ws_size;

    // workspace layout (f32 units). Total ~39 MiB.
    // GS splits: L0 h 0-3, L0 rest 4-8 (gate0 reads 0-8),
    //            L1 h 9-12, L1 rest 13-18 (gate1 reads 9-18).
    float* wsf   = (float*)d_ws;
    float* GS    = wsf;                        // 20 x SPLIT reserved (19 used)
    float* CTXP  = wsf + 5242880;              // 8 x 64 x 512 ctx partials
    float* QPf   = wsf + 5505024;              // 64 x 128 accumulated q
    u16*   MPROJ = (u16*)(wsf + 5513216);      // 64 x 1000 x 128 bf16
    u16*   AB0   = (u16*)(wsf + 9609216);      // 64 x 1664 bf16 (cols 0..640 used)
    u16*   AB1   = (u16*)(wsf + 9662464);      // 64 x 2560 bf16 (cols 0..1536 used)
    u16*   BTWM  = (u16*)(wsf + 9744384);      // 65536 bf16

    const u32* H0R = (const u32*)d_in[2];

    // L0: btprep + prenet + h-state GEMMs (whh0 -> splits 0-3, whh1 -> 9-12)
    prep_kernel<<<608, 256, 0, stream>>>(H0R, d_in[19], BTWM,
                                         d_in[0], d_in[8], d_in[9], d_in[10], d_in[11], AB0,
                                         d_in[2], d_in[13], d_in[4], d_in[16], GS);
    // L1: fused ctx + Mproj (merged dtype kernel, convert-at-load)
    ctxproj_kernel<<<dim3(8, 64), 512, 0, stream>>>(H0R, d_in[6], d_in[1], BTWM, CTXP, MPROJ);
    // L2: ctx reduce + packing + QP zero + xdec tail zeros
    pack0_kernel<<<64, 256, 0, stream>>>(H0R, CTXP, AB0, AB1, QPf, d_out);
    // L3/L4: LSTM layer 0 rest (K-rows 0..640 = xpre+ctx, wih0; 5 splits x 2 chunks = 320 blocks)
    gemm_kernel<<<dim3(64, 5), 256, 0, stream>>>(H0R, AB0, 1664, 640, d_in[12], d_in[12],
                                                 GS + (size_t)4 * SPLIT, 2);
    gate_kernel<<<256, 256, 0, stream>>>(H0R, GS, 9, d_in[14], d_in[2], d_in[3],
                                         d_in[18], 0, QPf, d_out, O_H0, O_C0, 0, AB1);
    // L5/L6: LSTM layer 1 rest (K-rows 0..1536 = h0n+ctx, wih1; 6 splits x 4 chunks = 384 blocks)
    gemm_kernel<<<dim3(64, 6), 256, 0, stream>>>(H0R, AB1, 2560, 1536, d_in[15], d_in[15],
                                                 GS + (size_t)13 * SPLIT, 4);
    gate_kernel<<<256, 256, 0, stream>>>(H0R, GS + (size_t)9 * SPLIT, 10, d_in[17], d_in[4], d_in[5],
                                         d_in[18], 1024, QPf, d_out, O_H1, O_C1, 1024, (u16*)nullptr);
    // L8: p = sigmoid(v . tanh(q + Mproj)) fused with w_new
    attn_kernel<<<dim3(16, 64), 256, 0, stream>>>(H0R, MPROJ, QPf, d_in[20], d_in[21], d_in[1], d_out);
}